// Round 12
// baseline (1256.957 us; speedup 1.0000x reference)
//
#include <hip/hip_runtime.h>
#include <math.h>

// Problem constants (B=2, H=16, L=2048, D=128, fp32 in/out, int32 mask)
constexpr int Bc_ = 2;
constexpr int Hc_ = 16;
constexpr int Lc_ = 2048;
constexpr int Dc_ = 128;
constexpr int BR  = 128;  // Q rows per block (4 waves x 32 rows, 32x32 MFMA)
constexpr int BC  = 32;   // K rows per tile
constexpr float SCALE_LOG2E = 0.08838834764831845f * 1.4426950408889634f;

typedef __attribute__((ext_vector_type(8)))  short        bf16x8;
typedef __attribute__((ext_vector_type(4)))  float        f32x4;
typedef __attribute__((ext_vector_type(16))) float        f32x16;
typedef __attribute__((ext_vector_type(4)))  int          i32x4;
typedef __attribute__((ext_vector_type(4)))  unsigned int u32x4;

__device__ __forceinline__ unsigned short f2bf(float f) {
  unsigned u = __builtin_bit_cast(unsigned, f);
  return (unsigned short)((u + 0x7fffu + ((u >> 16) & 1u)) >> 16);
}

__device__ __forceinline__ unsigned cvt_pk_bf16(float lo, float hi) {
  unsigned r;
  asm("v_cvt_pk_bf16_f32 %0, %1, %2" : "=v"(r) : "v"(lo), "v"(hi));
  return r;
}

// Workgroup barrier that does NOT drain vmcnt (unlike __syncthreads).
__device__ __forceinline__ void barrier_lgkm() {
  asm volatile("s_waitcnt lgkmcnt(0)\n\ts_barrier" ::: "memory");
}

constexpr int KS_STRIDE = 136;  // K tile rows (shorts)
constexpr int VT_STRIDE = 40;   // V^T rows (shorts, 32 k-cols + 8 pad)

// XOR swizzle (shorts), write==read, bijective, 16B-preserving (R7-verified).
__device__ __forceinline__ int swz(int row, int colShorts) {
  return colShorts ^ (((row >> 3) & 3) << 3);
}

// ===========================================================================
// R12 = R11 (best: 812 total, attn ~247us) + SPLIT-K x2.
// Rationale: R7 proved the 2-barrier tile loop SELF-PACES (~300us with zero
// mask traffic) — latency-serialization, not delivery. Occupancy is pinned
// at 8 waves/CU by Q-parallelism (2048 waves total). The no-max softmax
// makes split-KV exactly mergeable: unnormalized O and lsum partials ADD.
// Split KV into 2 halves -> 1024 blocks; launch_bounds(256,3) -> 3 blocks/CU
// resident -> 12 waves/CU (1.5x latency hiding). Half 0 -> Out (unnorm),
// half 1 -> ws; lsums -> ws; merge kernel normalizes. ws need: 34.1 MB;
// fallback (ws too small) = R11 verbatim.
// Tile math/layout identical to R11 (verified).
// ===========================================================================
#define TILE_BODY(KB, MC, MN)                                               \
  {                                                                         \
    /* 1. stage current K regs -> LDS (bf16, swizzled row-major) */         \
    {                                                                       \
      u32x4 a, b;                                                           \
      a[0] = cvt_pk_bf16(kr[0][0], kr[0][1]);                               \
      a[1] = cvt_pk_bf16(kr[0][2], kr[0][3]);                               \
      a[2] = cvt_pk_bf16(kr[1][0], kr[1][1]);                               \
      a[3] = cvt_pk_bf16(kr[1][2], kr[1][3]);                               \
      b[0] = cvt_pk_bf16(kr[2][0], kr[2][1]);                               \
      b[1] = cvt_pk_bf16(kr[2][2], kr[2][3]);                               \
      b[2] = cvt_pk_bf16(kr[3][0], kr[3][1]);                               \
      b[3] = cvt_pk_bf16(kr[3][2], kr[3][3]);                               \
      *(u32x4*)&Ks[krow * KS_STRIDE + swz(krow, kcg * 16)]     = a;         \
      *(u32x4*)&Ks[krow * KS_STRIDE + swz(krow, kcg * 16 + 8)] = b;         \
    }                                                                       \
    /* stage current V regs -> LDS transposed (scatter, swizzled) */        \
    _Pragma("unroll")                                                       \
    for (int c4 = 0; c4 < 4; ++c4) {                                        \
      const unsigned lov = cvt_pk_bf16(vr[c4][0], vr[c4][1]);               \
      const unsigned hiv = cvt_pk_bf16(vr[c4][2], vr[c4][3]);               \
      const int r0 = vcg * 16 + c4 * 4;                                     \
      Vt[(r0 + 0) * VT_STRIDE + swz(r0 + 0, vrow)] = (unsigned short)lov;   \
      Vt[(r0 + 1) * VT_STRIDE + swz(r0 + 1, vrow)] = (unsigned short)(lov >> 16); \
      Vt[(r0 + 2) * VT_STRIDE + swz(r0 + 2, vrow)] = (unsigned short)hiv;   \
      Vt[(r0 + 3) * VT_STRIDE + swz(r0 + 3, vrow)] = (unsigned short)(hiv >> 16); \
    }                                                                       \
    /* 2. issue next-tile K/V + mask loads (1-deep, cacheable) */           \
    {                                                                       \
      const int kbn = ((KB) + BC) & (Lc_ - 1);                              \
      const float* kp = kbase_g + (size_t)kbn * Dc_;                        \
      const float* vp = vbase_g + (size_t)kbn * Dc_;                        \
      kr[0] = *(const f32x4*)(kp + 0);  kr[1] = *(const f32x4*)(kp + 4);    \
      kr[2] = *(const f32x4*)(kp + 8);  kr[3] = *(const f32x4*)(kp + 12);   \
      vr[0] = *(const f32x4*)(vp + 0);  vr[1] = *(const f32x4*)(vp + 4);    \
      vr[2] = *(const f32x4*)(vp + 8);  vr[3] = *(const f32x4*)(vp + 12);   \
      MN##0 = *(const i32x4*)(mbase_g + kbn);                               \
      MN##1 = *(const i32x4*)(mbase_g + kbn + 8);                           \
      MN##2 = *(const i32x4*)(mbase_g + kbn + 16);                          \
      MN##3 = *(const i32x4*)(mbase_g + kbn + 24);                          \
    }                                                                       \
    /* 3. barrier (lgkm only) — publishes Ks/Vt */                          \
    barrier_lgkm();                                                         \
    /* 4. S^T = K (Q*scale)^T : 8 MFMAs as TWO independent 4-chains */      \
    f32x16 s0 = (f32x16)0.0f, s1 = (f32x16)0.0f;                            \
    __builtin_amdgcn_s_setprio(1);                                          \
    _Pragma("unroll")                                                       \
    for (int st = 0; st < 8; st += 2) {                                     \
      const bf16x8 kf0 = *(const bf16x8*)&Ks[l31 * KS_STRIDE + swz(l31, st * 16 + hi8)]; \
      s0 = __builtin_amdgcn_mfma_f32_32x32x16_bf16(kf0, qf[st], s0, 0, 0, 0); \
      const bf16x8 kf1 = *(const bf16x8*)&Ks[l31 * KS_STRIDE + swz(l31, (st + 1) * 16 + hi8)]; \
      s1 = __builtin_amdgcn_mfma_f32_32x32x16_bf16(kf1, qf[st + 1], s1, 0, 0, 0); \
    }                                                                       \
    __builtin_amdgcn_s_setprio(0);                                          \
    const f32x16 s = s0 + s1;                                               \
    /* 5. p = mask ? exp2(s) : 0 ; scalar row-sum; PV A-frags in register */\
    bf16x8 pa0, pa1;                                                        \
    {                                                                       \
      const float p0  = ((MC##0)[0] != 0) ? exp2f(s[0])  : 0.0f;            \
      const float p1  = ((MC##0)[1] != 0) ? exp2f(s[1])  : 0.0f;            \
      const float p2  = ((MC##0)[2] != 0) ? exp2f(s[2])  : 0.0f;            \
      const float p3  = ((MC##0)[3] != 0) ? exp2f(s[3])  : 0.0f;            \
      const float p4  = ((MC##1)[0] != 0) ? exp2f(s[4])  : 0.0f;            \
      const float p5  = ((MC##1)[1] != 0) ? exp2f(s[5])  : 0.0f;            \
      const float p6  = ((MC##1)[2] != 0) ? exp2f(s[6])  : 0.0f;            \
      const float p7  = ((MC##1)[3] != 0) ? exp2f(s[7])  : 0.0f;            \
      const float p8  = ((MC##2)[0] != 0) ? exp2f(s[8])  : 0.0f;            \
      const float p9  = ((MC##2)[1] != 0) ? exp2f(s[9])  : 0.0f;            \
      const float p10 = ((MC##2)[2] != 0) ? exp2f(s[10]) : 0.0f;            \
      const float p11 = ((MC##2)[3] != 0) ? exp2f(s[11]) : 0.0f;            \
      const float p12 = ((MC##3)[0] != 0) ? exp2f(s[12]) : 0.0f;            \
      const float p13 = ((MC##3)[1] != 0) ? exp2f(s[13]) : 0.0f;            \
      const float p14 = ((MC##3)[2] != 0) ? exp2f(s[14]) : 0.0f;            \
      const float p15 = ((MC##3)[3] != 0) ? exp2f(s[15]) : 0.0f;            \
      lsum += (((p0 + p1) + (p2 + p3)) + ((p4 + p5) + (p6 + p7)))           \
            + (((p8 + p9) + (p10 + p11)) + ((p12 + p13) + (p14 + p15)));    \
      const unsigned c0 = cvt_pk_bf16(p0,  p1),  c1 = cvt_pk_bf16(p2,  p3); \
      const unsigned c2 = cvt_pk_bf16(p4,  p5),  c3 = cvt_pk_bf16(p6,  p7); \
      const unsigned c4 = cvt_pk_bf16(p8,  p9),  c5 = cvt_pk_bf16(p10, p11);\
      const unsigned c6 = cvt_pk_bf16(p12, p13), c7 = cvt_pk_bf16(p14, p15);\
      const unsigned x0 = (unsigned)__shfl_xor((int)c0, 32);                \
      const unsigned x1 = (unsigned)__shfl_xor((int)c1, 32);                \
      const unsigned x2 = (unsigned)__shfl_xor((int)c2, 32);                \
      const unsigned x3 = (unsigned)__shfl_xor((int)c3, 32);                \
      const unsigned x4 = (unsigned)__shfl_xor((int)c4, 32);                \
      const unsigned x5 = (unsigned)__shfl_xor((int)c5, 32);                \
      const unsigned x6 = (unsigned)__shfl_xor((int)c6, 32);                \
      const unsigned x7 = (unsigned)__shfl_xor((int)c7, 32);                \
      u32x4 a0, a1;                                                         \
      a0[0] = lo ? c0 : x2;  a0[1] = lo ? c1 : x3;                          \
      a0[2] = lo ? x0 : c2;  a0[3] = lo ? x1 : c3;                          \
      a1[0] = lo ? c4 : x6;  a1[1] = lo ? c5 : x7;                          \
      a1[2] = lo ? x4 : c6;  a1[3] = lo ? x5 : c7;                          \
      pa0 = __builtin_bit_cast(bf16x8, a0);                                 \
      pa1 = __builtin_bit_cast(bf16x8, a1);                                 \
    }                                                                       \
    /* 6. O += P V */                                                       \
    __builtin_amdgcn_s_setprio(1);                                          \
    _Pragma("unroll")                                                       \
    for (int nb = 0; nb < 4; ++nb) {                                        \
      const int vrw0 = nb * 32 + l31;                                       \
      const bf16x8 vf0 = *(const bf16x8*)&Vt[vrw0 * VT_STRIDE + swz(vrw0, hi8)]; \
      acc[nb] = __builtin_amdgcn_mfma_f32_32x32x16_bf16(pa0, vf0, acc[nb], 0, 0, 0); \
      const bf16x8 vf1 = *(const bf16x8*)&Vt[vrw0 * VT_STRIDE + swz(vrw0, 16 + hi8)]; \
      acc[nb] = __builtin_amdgcn_mfma_f32_32x32x16_bf16(pa1, vf1, acc[nb], 0, 0, 0); \
    }                                                                       \
    __builtin_amdgcn_s_setprio(0);                                          \
    /* 7. protect LDS before next overwrite */                              \
    barrier_lgkm();                                                         \
  }

// launch_bounds(256,3): VGPR cap ~170 >= ~136 demand (R11 level; R3's
// (256,3) spill was at ~200 demand). DO NOT go to 4 waves/EU (cap 128 ->
// 2.5 GB spill, measured twice). SPLIT: 1024 blocks -> 3 resident/CU =
// 12 waves/CU. Fallback: 512 blocks -> 2/CU (R11 behavior).
template <bool SPLIT>
__global__ __launch_bounds__(256, 3) void attn_fwd(
    const float* __restrict__ Q, const float* __restrict__ K,
    const float* __restrict__ V, const int* __restrict__ Mask,
    float* __restrict__ Out, float* __restrict__ WsO,
    float* __restrict__ WsL) {
  int bh, qblk, kv0;
  float* Og;
  float* Lg = nullptr;
  if constexpr (SPLIT) {
    // XCD decode: 1024 blocks; each XCD gets 4 bh; halves of a qblk adjacent.
    const int id  = blockIdx.x;
    const int xcd = id & 7;
    const int sub = id >> 3;                 // 0..127
    bh = xcd * 4 + (sub >> 5);
    const int rem = sub & 31;
    qblk = rem >> 1;
    const int half = rem & 1;
    kv0 = half * (Lc_ / 2);
    Og = (half == 0 ? Out : WsO) + (size_t)bh * Lc_ * Dc_;
    Lg = WsL + (size_t)half * (Bc_ * Hc_ * Lc_) + (size_t)bh * Lc_;
  } else {
    const int id  = blockIdx.x;
    const int xcd = id & 7;
    const int sub = id >> 3;                 // 0..63
    bh = xcd * 4 + (sub >> 4);
    qblk = sub & 15;
    kv0 = 0;
    Og = Out + (size_t)bh * Lc_ * Dc_;
  }
  const int kv1 = SPLIT ? (kv0 + Lc_ / 2) : Lc_;

  const int tid  = threadIdx.x;
  const int w    = tid >> 6;
  const int lane = tid & 63;
  const int l31  = lane & 31;
  const int hi   = lane >> 5;
  const int hi8  = hi * 8;
  const bool lo  = (hi == 0);

  const float* Qg = Q + (size_t)bh * Lc_ * Dc_;
  const float* Kg = K + (size_t)bh * Lc_ * Dc_;
  const float* Vg = V + (size_t)bh * Lc_ * Dc_;
  const int*   Mg = Mask + (size_t)bh * Lc_ * Lc_;

  const int qr0 = qblk * BR + w * 32;

  __shared__ alignas(16) unsigned short Ks[BC * KS_STRIDE];
  __shared__ alignas(16) unsigned short Vt[Dc_ * VT_STRIDE];

  // ---- Q fragments (B-operand of 32x32x16), loaded once, pre-scaled ----
  bf16x8 qf[8];
  {
    const float* qrow = Qg + (size_t)(qr0 + l31) * Dc_ + hi8;
#pragma unroll
    for (int st = 0; st < 8; ++st) {
      const f32x4 a = *(const f32x4*)(qrow + st * 16);
      const f32x4 b = *(const f32x4*)(qrow + st * 16 + 4);
      bf16x8 f;
      f[0] = (short)f2bf(a[0] * SCALE_LOG2E); f[1] = (short)f2bf(a[1] * SCALE_LOG2E);
      f[2] = (short)f2bf(a[2] * SCALE_LOG2E); f[3] = (short)f2bf(a[3] * SCALE_LOG2E);
      f[4] = (short)f2bf(b[0] * SCALE_LOG2E); f[5] = (short)f2bf(b[1] * SCALE_LOG2E);
      f[6] = (short)f2bf(b[2] * SCALE_LOG2E); f[7] = (short)f2bf(b[3] * SCALE_LOG2E);
      qf[st] = f;
    }
  }

  f32x16 acc[4];
#pragma unroll
  for (int i = 0; i < 4; ++i) acc[i] = (f32x16)0.0f;
  float lsum = 0.0f;

  const int krow = tid >> 3;
  const int kcg  = tid & 7;
  const int vrow = tid & 31;
  const int vcg  = tid >> 5;

  const float* kbase_g = Kg + (size_t)krow * Dc_ + kcg * 16;
  const float* vbase_g = Vg + (size_t)vrow * Dc_ + vcg * 16;
  const int*   mbase_g = Mg + (size_t)(qr0 + l31) * Lc_ + hi * 4;

  f32x4 kr[4], vr[4];
  i32x4 mA0, mA1, mA2, mA3, mB0, mB1, mB2, mB3;

  {
    const float* kp = kbase_g + (size_t)kv0 * Dc_;
    const float* vp = vbase_g + (size_t)kv0 * Dc_;
    kr[0] = *(const f32x4*)(kp + 0);  kr[1] = *(const f32x4*)(kp + 4);
    kr[2] = *(const f32x4*)(kp + 8);  kr[3] = *(const f32x4*)(kp + 12);
    vr[0] = *(const f32x4*)(vp + 0);  vr[1] = *(const f32x4*)(vp + 4);
    vr[2] = *(const f32x4*)(vp + 8);  vr[3] = *(const f32x4*)(vp + 12);
  }
  mA0 = *(const i32x4*)(mbase_g + kv0);
  mA1 = *(const i32x4*)(mbase_g + kv0 + 8);
  mA2 = *(const i32x4*)(mbase_g + kv0 + 16);
  mA3 = *(const i32x4*)(mbase_g + kv0 + 24);

#pragma unroll 1
  for (int kb = kv0; kb < kv1; kb += 2 * BC) {
    TILE_BODY(kb,      mA, mB)
    TILE_BODY(kb + BC, mB, mA)
  }

  // ---- epilogue ----
  lsum += __shfl_xor(lsum, 32);   // lanes l, l^32 hold total for row qr0+l31
  if constexpr (SPLIT) {
    if (lane < 32) Lg[qr0 + l31] = lsum;   // per-wave 32 contiguous floats
#pragma unroll
    for (int r = 0; r < 16; ++r) {
      const int qrow_r = (r & 3) + 8 * (r >> 2) + 4 * hi;
      float* orow = Og + (size_t)(qr0 + qrow_r) * Dc_ + l31;
#pragma unroll
      for (int nb = 0; nb < 4; ++nb)
        __builtin_nontemporal_store(acc[nb][r], orow + nb * 32);  // UNNORMALIZED
    }
  } else {
    const float inv = 1.0f / lsum;
#pragma unroll
    for (int r = 0; r < 16; ++r) {
      const int qrow_r = (r & 3) + 8 * (r >> 2) + 4 * hi;
      const float rinv = __shfl(inv, qrow_r);
      float* orow = Og + (size_t)(qr0 + qrow_r) * Dc_ + l31;
#pragma unroll
      for (int nb = 0; nb < 4; ++nb)
        __builtin_nontemporal_store(acc[nb][r] * rinv, orow + nb * 32);
    }
  }
}

// Merge: Out = (Out + WsO) / (l0 + l1). 8.4M floats as float4 per thread.
__global__ __launch_bounds__(256) void merge_halves(
    float* __restrict__ Out, const float* __restrict__ WsO,
    const float* __restrict__ WsL) {
  const size_t t    = (size_t)blockIdx.x * 256 + threadIdx.x;
  const size_t base = t * 4;                          // element index
  const int    row  = (int)(base >> 7);               // global q-row 0..65535
  const float  l0   = WsL[row];
  const float  l1   = WsL[Bc_ * Hc_ * Lc_ + row];
  const float  inv  = 1.0f / (l0 + l1);
  const f32x4 o0 = *(const f32x4*)(Out + base);
  const f32x4 o1 = *(const f32x4*)(WsO + base);
  f32x4 r;
  r[0] = (o0[0] + o1[0]) * inv;  r[1] = (o0[1] + o1[1]) * inv;
  r[2] = (o0[2] + o1[2]) * inv;  r[3] = (o0[3] + o1[3]) * inv;
  *(f32x4*)(Out + base) = r;
}

extern "C" void kernel_launch(void* const* d_in, const int* in_sizes, int n_in,
                              void* d_out, int out_size, void* d_ws, size_t ws_size,
                              hipStream_t stream) {
  const float* Q    = (const float*)d_in[0];
  const float* K    = (const float*)d_in[1];
  const float* V    = (const float*)d_in[2];
  const int*   Mask = (const int*)d_in[3];
  float*       Out  = (float*)d_out;

  const size_t wsO_bytes = (size_t)Bc_ * Hc_ * Lc_ * Dc_ * sizeof(float);   // 33.6 MB
  const size_t wsL_bytes = (size_t)2 * Bc_ * Hc_ * Lc_ * sizeof(float);     // 0.5 MB

  if (d_ws != nullptr && ws_size >= wsO_bytes + wsL_bytes) {
    float* WsO = (float*)d_ws;
    float* WsL = (float*)((char*)d_ws + wsO_bytes);
    attn_fwd<true><<<dim3(1024), dim3(256), 0, stream>>>(Q, K, V, Mask, Out, WsO, WsL);
    const int nthr = Bc_ * Hc_ * Lc_ * Dc_ / 4;       // 2.1M float4 threads
    merge_halves<<<dim3(nthr / 256), dim3(256), 0, stream>>>(Out, WsO, WsL);
  } else {
    attn_fwd<false><<<dim3(512), dim3(256), 0, stream>>>(Q, K, V, Mask, Out,
                                                         nullptr, nullptr);
  }
}

// Round 13
// 812.193 us; speedup vs baseline: 1.5476x; 1.5476x over previous
//
#include <hip/hip_runtime.h>
#include <math.h>

// Problem constants (B=2, H=16, L=2048, D=128, fp32 in/out, int32 mask)
constexpr int Bc_ = 2;
constexpr int Hc_ = 16;
constexpr int Lc_ = 2048;
constexpr int Dc_ = 128;
constexpr int BR  = 128;  // Q rows per block (4 waves x 32 rows, 32x32 MFMA)
constexpr int BC  = 32;   // K rows per tile
// 1/sqrt(128) * log2(e): exp(x) == exp2(x*log2e); fold log2e into Q pre-scale.
constexpr float SCALE_LOG2E = 0.08838834764831845f * 1.4426950408889634f;

typedef __attribute__((ext_vector_type(8)))  short        bf16x8;
typedef __attribute__((ext_vector_type(4)))  float        f32x4;
typedef __attribute__((ext_vector_type(16))) float        f32x16;
typedef __attribute__((ext_vector_type(4)))  int          i32x4;
typedef __attribute__((ext_vector_type(4)))  unsigned int u32x4;

// fp32 -> bf16 RNE (scalar; only for the one-time Q fragment build)
__device__ __forceinline__ unsigned short f2bf(float f) {
  unsigned u = __builtin_bit_cast(unsigned, f);
  return (unsigned short)((u + 0x7fffu + ((u >> 16) & 1u)) >> 16);
}

// packed fp32x2 -> bf16x2 in ONE VALU op
__device__ __forceinline__ unsigned cvt_pk_bf16(float lo, float hi) {
  unsigned r;
  asm("v_cvt_pk_bf16_f32 %0, %1, %2" : "=v"(r) : "v"(lo), "v"(hi));
  return r;
}

// Workgroup barrier that does NOT drain vmcnt (unlike __syncthreads).
// LDS visibility needs lgkmcnt(0) only; register-prefetch global loads
// stay in flight across the barrier.
__device__ __forceinline__ void barrier_lgkm() {
  asm volatile("s_waitcnt lgkmcnt(0)\n\ts_barrier" ::: "memory");
}

constexpr int KS_STRIDE = 136;  // K tile rows (shorts)
constexpr int VT_STRIDE = 40;   // V^T rows (shorts, 32 k-cols + 8 pad)

// XOR swizzle (shorts): rows r, r+8, r+16, r+24 (same base bank-phase) get
// 4 distinct 16B slots. Applied identically on write and read (bijective,
// preserves 16B alignment). R7-verified; conflicts 2.4e7 -> 1.47e7.
__device__ __forceinline__ int swz(int row, int colShorts) {
  return colShorts ^ (((row >> 3) & 3) << 3);
}

// ===========================================================================
// R13 = R11 VERBATIM (best measured: total 812.3, attn ~247us).
// R12's split-K spilled: (256,3) leaves ~168 total regs/wave, acc holds 64
// -> ~104 arch VGPRs for a ~136-reg pipeline -> VGPR capped at 84, 488 MB
// scratch writes, attn 685us. Third occurrence of the same failure mode
// (R3, R12): with a 64-AGPR accumulator this kernel runs at 2 waves/EU,
// period. Occupancy lever structurally unavailable at this tile shape.
// Session ledger of measured-good levers (all present here):
//   32x32 MFMA swapped-operand structure + in-register P build (R4)
//   s_setprio + LDS XOR-swizzle (R8, +3us)
//   XCD-aware bijective block swizzle (R10, +11us; FETCH 651->391 MB)
//   cacheable mask loads + dual-accumulator QK^T (R11, +32us)
// Measured-bad: deep register prefetch (spills: R3/R9/R12), mask pre-pass
// (serializes + L3 thrash: R7), dbuf/1-barrier (null: R7), pack_mask 2-pass
// (pack tax eats gain: R5), 4 waves/EU (2.5GB spill: R2).
// ===========================================================================
#define TILE_BODY(KB, MC, MN)                                               \
  {                                                                         \
    /* 1. stage current K regs -> LDS (bf16, swizzled row-major) */         \
    {                                                                       \
      u32x4 a, b;                                                           \
      a[0] = cvt_pk_bf16(kr[0][0], kr[0][1]);                               \
      a[1] = cvt_pk_bf16(kr[0][2], kr[0][3]);                               \
      a[2] = cvt_pk_bf16(kr[1][0], kr[1][1]);                               \
      a[3] = cvt_pk_bf16(kr[1][2], kr[1][3]);                               \
      b[0] = cvt_pk_bf16(kr[2][0], kr[2][1]);                               \
      b[1] = cvt_pk_bf16(kr[2][2], kr[2][3]);                               \
      b[2] = cvt_pk_bf16(kr[3][0], kr[3][1]);                               \
      b[3] = cvt_pk_bf16(kr[3][2], kr[3][3]);                               \
      *(u32x4*)&Ks[krow * KS_STRIDE + swz(krow, kcg * 16)]     = a;         \
      *(u32x4*)&Ks[krow * KS_STRIDE + swz(krow, kcg * 16 + 8)] = b;         \
    }                                                                       \
    /* stage current V regs -> LDS transposed (scatter, swizzled) */        \
    _Pragma("unroll")                                                       \
    for (int c4 = 0; c4 < 4; ++c4) {                                        \
      const unsigned lov = cvt_pk_bf16(vr[c4][0], vr[c4][1]);               \
      const unsigned hiv = cvt_pk_bf16(vr[c4][2], vr[c4][3]);               \
      const int r0 = vcg * 16 + c4 * 4;                                     \
      Vt[(r0 + 0) * VT_STRIDE + swz(r0 + 0, vrow)] = (unsigned short)lov;   \
      Vt[(r0 + 1) * VT_STRIDE + swz(r0 + 1, vrow)] = (unsigned short)(lov >> 16); \
      Vt[(r0 + 2) * VT_STRIDE + swz(r0 + 2, vrow)] = (unsigned short)hiv;   \
      Vt[(r0 + 3) * VT_STRIDE + swz(r0 + 3, vrow)] = (unsigned short)(hiv >> 16); \
    }                                                                       \
    /* 2. issue next-tile K/V + mask loads (1-deep, cacheable). All stay    \
          in flight across the lgkm-only barrier. */                        \
    {                                                                       \
      const int kbn = ((KB) + BC) & (Lc_ - 1);                              \
      const float* kp = kbase_g + (size_t)kbn * Dc_;                        \
      const float* vp = vbase_g + (size_t)kbn * Dc_;                        \
      kr[0] = *(const f32x4*)(kp + 0);  kr[1] = *(const f32x4*)(kp + 4);    \
      kr[2] = *(const f32x4*)(kp + 8);  kr[3] = *(const f32x4*)(kp + 12);   \
      vr[0] = *(const f32x4*)(vp + 0);  vr[1] = *(const f32x4*)(vp + 4);    \
      vr[2] = *(const f32x4*)(vp + 8);  vr[3] = *(const f32x4*)(vp + 12);   \
      MN##0 = *(const i32x4*)(mbase_g + kbn);                               \
      MN##1 = *(const i32x4*)(mbase_g + kbn + 8);                           \
      MN##2 = *(const i32x4*)(mbase_g + kbn + 16);                          \
      MN##3 = *(const i32x4*)(mbase_g + kbn + 24);                          \
    }                                                                       \
    /* 3. barrier (lgkm only) — publishes Ks/Vt */                          \
    barrier_lgkm();                                                         \
    /* 4. S^T = K (Q*scale)^T : 8 MFMAs as TWO independent 4-chains */      \
    f32x16 s0 = (f32x16)0.0f, s1 = (f32x16)0.0f;                            \
    __builtin_amdgcn_s_setprio(1);                                          \
    _Pragma("unroll")                                                       \
    for (int st = 0; st < 8; st += 2) {                                     \
      const bf16x8 kf0 = *(const bf16x8*)&Ks[l31 * KS_STRIDE + swz(l31, st * 16 + hi8)]; \
      s0 = __builtin_amdgcn_mfma_f32_32x32x16_bf16(kf0, qf[st], s0, 0, 0, 0); \
      const bf16x8 kf1 = *(const bf16x8*)&Ks[l31 * KS_STRIDE + swz(l31, (st + 1) * 16 + hi8)]; \
      s1 = __builtin_amdgcn_mfma_f32_32x32x16_bf16(kf1, qf[st + 1], s1, 0, 0, 0); \
    }                                                                       \
    __builtin_amdgcn_s_setprio(0);                                          \
    const f32x16 s = s0 + s1;                                               \
    /* 5. p = mask ? exp2(s) : 0 ; per-lane scalar row-sum; PV A-frags in   \
          register via cvt_pk + cross-half exchange (no LDS). */            \
    bf16x8 pa0, pa1;                                                        \
    {                                                                       \
      const float p0  = ((MC##0)[0] != 0) ? exp2f(s[0])  : 0.0f;            \
      const float p1  = ((MC##0)[1] != 0) ? exp2f(s[1])  : 0.0f;            \
      const float p2  = ((MC##0)[2] != 0) ? exp2f(s[2])  : 0.0f;            \
      const float p3  = ((MC##0)[3] != 0) ? exp2f(s[3])  : 0.0f;            \
      const float p4  = ((MC##1)[0] != 0) ? exp2f(s[4])  : 0.0f;            \
      const float p5  = ((MC##1)[1] != 0) ? exp2f(s[5])  : 0.0f;            \
      const float p6  = ((MC##1)[2] != 0) ? exp2f(s[6])  : 0.0f;            \
      const float p7  = ((MC##1)[3] != 0) ? exp2f(s[7])  : 0.0f;            \
      const float p8  = ((MC##2)[0] != 0) ? exp2f(s[8])  : 0.0f;            \
      const float p9  = ((MC##2)[1] != 0) ? exp2f(s[9])  : 0.0f;            \
      const float p10 = ((MC##2)[2] != 0) ? exp2f(s[10]) : 0.0f;            \
      const float p11 = ((MC##2)[3] != 0) ? exp2f(s[11]) : 0.0f;            \
      const float p12 = ((MC##3)[0] != 0) ? exp2f(s[12]) : 0.0f;            \
      const float p13 = ((MC##3)[1] != 0) ? exp2f(s[13]) : 0.0f;            \
      const float p14 = ((MC##3)[2] != 0) ? exp2f(s[14]) : 0.0f;            \
      const float p15 = ((MC##3)[3] != 0) ? exp2f(s[15]) : 0.0f;            \
      lsum += (((p0 + p1) + (p2 + p3)) + ((p4 + p5) + (p6 + p7)))           \
            + (((p8 + p9) + (p10 + p11)) + ((p12 + p13) + (p14 + p15)));    \
      const unsigned c0 = cvt_pk_bf16(p0,  p1),  c1 = cvt_pk_bf16(p2,  p3); \
      const unsigned c2 = cvt_pk_bf16(p4,  p5),  c3 = cvt_pk_bf16(p6,  p7); \
      const unsigned c4 = cvt_pk_bf16(p8,  p9),  c5 = cvt_pk_bf16(p10, p11);\
      const unsigned c6 = cvt_pk_bf16(p12, p13), c7 = cvt_pk_bf16(p14, p15);\
      const unsigned x0 = (unsigned)__shfl_xor((int)c0, 32);                \
      const unsigned x1 = (unsigned)__shfl_xor((int)c1, 32);                \
      const unsigned x2 = (unsigned)__shfl_xor((int)c2, 32);                \
      const unsigned x3 = (unsigned)__shfl_xor((int)c3, 32);                \
      const unsigned x4 = (unsigned)__shfl_xor((int)c4, 32);                \
      const unsigned x5 = (unsigned)__shfl_xor((int)c5, 32);                \
      const unsigned x6 = (unsigned)__shfl_xor((int)c6, 32);                \
      const unsigned x7 = (unsigned)__shfl_xor((int)c7, 32);                \
      u32x4 a0, a1;                                                         \
      a0[0] = lo ? c0 : x2;  a0[1] = lo ? c1 : x3;                          \
      a0[2] = lo ? x0 : c2;  a0[3] = lo ? x1 : c3;                          \
      a1[0] = lo ? c4 : x6;  a1[1] = lo ? c5 : x7;                          \
      a1[2] = lo ? x4 : c6;  a1[3] = lo ? x5 : c7;                          \
      pa0 = __builtin_bit_cast(bf16x8, a0);                                 \
      pa1 = __builtin_bit_cast(bf16x8, a1);                                 \
    }                                                                       \
    /* 6. O += P V : 4 d-blocks x 2 k-halves, B = V^T rows from LDS */      \
    __builtin_amdgcn_s_setprio(1);                                          \
    _Pragma("unroll")                                                       \
    for (int nb = 0; nb < 4; ++nb) {                                        \
      const int vrw0 = nb * 32 + l31;                                       \
      const bf16x8 vf0 = *(const bf16x8*)&Vt[vrw0 * VT_STRIDE + swz(vrw0, hi8)]; \
      acc[nb] = __builtin_amdgcn_mfma_f32_32x32x16_bf16(pa0, vf0, acc[nb], 0, 0, 0); \
      const bf16x8 vf1 = *(const bf16x8*)&Vt[vrw0 * VT_STRIDE + swz(vrw0, 16 + hi8)]; \
      acc[nb] = __builtin_amdgcn_mfma_f32_32x32x16_bf16(pa1, vf1, acc[nb], 0, 0, 0); \
    }                                                                       \
    __builtin_amdgcn_s_setprio(0);                                          \
    /* 7. protect LDS before next overwrite */                              \
    barrier_lgkm();                                                         \
  }

// launch_bounds(256, 2): ~136 live regs. With the 64-reg accumulator, 2
// waves/EU is the ONLY non-spilling occupancy (3 waves/EU leaves ~104 arch
// VGPRs -> spills; measured R3, R12. 4 waves/EU -> 2.5 GB spill; R2).
// Grid 512 = exactly 2 blocks/CU. LDS: Ks 8704 + Vt 10240 = 18944 B.
__global__ __launch_bounds__(256, 2) void attn_fwd(
    const float* __restrict__ Q, const float* __restrict__ K,
    const float* __restrict__ V, const int* __restrict__ Mask,
    float* __restrict__ Out) {
  // XCD-aware bijective decode: xcd = id%8 (HW round-robin). Each XCD gets
  // bh in [4*xcd, 4*xcd+4), qblk sequential -> K/V (2MB/bh) L2-resident,
  // mask stream order de-thrashes L3 across dispatches (R9: FETCH 651->391).
  const int id   = blockIdx.x;
  const int xcd  = id & 7;
  const int sub  = id >> 3;          // 0..63
  const int bh   = xcd * 4 + (sub >> 4);
  const int qblk = sub & 15;

  const int tid  = threadIdx.x;
  const int w    = tid >> 6;
  const int lane = tid & 63;
  const int l31  = lane & 31;
  const int hi   = lane >> 5;
  const int hi8  = hi * 8;
  const bool lo  = (hi == 0);

  const float* Qg = Q + (size_t)bh * Lc_ * Dc_;
  const float* Kg = K + (size_t)bh * Lc_ * Dc_;
  const float* Vg = V + (size_t)bh * Lc_ * Dc_;
  const int*   Mg = Mask + (size_t)bh * Lc_ * Lc_;
  float*       Og = Out + (size_t)bh * Lc_ * Dc_;

  const int qr0 = qblk * BR + w * 32;

  __shared__ alignas(16) unsigned short Ks[BC * KS_STRIDE];
  __shared__ alignas(16) unsigned short Vt[Dc_ * VT_STRIDE];

  // ---- Q fragments (B-operand of 32x32x16), loaded once, pre-scaled ----
  bf16x8 qf[8];
  {
    const float* qrow = Qg + (size_t)(qr0 + l31) * Dc_ + hi8;
#pragma unroll
    for (int st = 0; st < 8; ++st) {
      const f32x4 a = *(const f32x4*)(qrow + st * 16);
      const f32x4 b = *(const f32x4*)(qrow + st * 16 + 4);
      bf16x8 f;
      f[0] = (short)f2bf(a[0] * SCALE_LOG2E); f[1] = (short)f2bf(a[1] * SCALE_LOG2E);
      f[2] = (short)f2bf(a[2] * SCALE_LOG2E); f[3] = (short)f2bf(a[3] * SCALE_LOG2E);
      f[4] = (short)f2bf(b[0] * SCALE_LOG2E); f[5] = (short)f2bf(b[1] * SCALE_LOG2E);
      f[6] = (short)f2bf(b[2] * SCALE_LOG2E); f[7] = (short)f2bf(b[3] * SCALE_LOG2E);
      qf[st] = f;
    }
  }

  f32x16 acc[4];
#pragma unroll
  for (int i = 0; i < 4; ++i) acc[i] = (f32x16)0.0f;
  float lsum = 0.0f;

  const int krow = tid >> 3;   // 0..31, 8 threads/row (coalesced 64B)
  const int kcg  = tid & 7;
  const int vrow = tid & 31;
  const int vcg  = tid >> 5;

  const float* kbase_g = Kg + (size_t)krow * Dc_ + kcg * 16;
  const float* vbase_g = Vg + (size_t)vrow * Dc_ + vcg * 16;
  const int*   mbase_g = Mg + (size_t)(qr0 + l31) * Lc_ + hi * 4;

  f32x4 kr[4], vr[4];
  i32x4 mA0, mA1, mA2, mA3, mB0, mB1, mB2, mB3;

  kr[0] = *(const f32x4*)(kbase_g + 0);  kr[1] = *(const f32x4*)(kbase_g + 4);
  kr[2] = *(const f32x4*)(kbase_g + 8);  kr[3] = *(const f32x4*)(kbase_g + 12);
  vr[0] = *(const f32x4*)(vbase_g + 0);  vr[1] = *(const f32x4*)(vbase_g + 4);
  vr[2] = *(const f32x4*)(vbase_g + 8);  vr[3] = *(const f32x4*)(vbase_g + 12);
  mA0 = *(const i32x4*)(mbase_g);
  mA1 = *(const i32x4*)(mbase_g + 8);
  mA2 = *(const i32x4*)(mbase_g + 16);
  mA3 = *(const i32x4*)(mbase_g + 24);

#pragma unroll 1
  for (int kb = 0; kb < Lc_; kb += 2 * BC) {
    TILE_BODY(kb,      mA, mB)
    TILE_BODY(kb + BC, mB, mA)
  }

  // ---- epilogue: combine k-halves' sums, normalize, store ----
  lsum += __shfl_xor(lsum, 32);
  const float inv = 1.0f / lsum;
#pragma unroll
  for (int r = 0; r < 16; ++r) {
    const int qrow_r = (r & 3) + 8 * (r >> 2) + 4 * hi;
    const float rinv = __shfl(inv, qrow_r);
    float* orow = Og + (size_t)(qr0 + qrow_r) * Dc_ + l31;
#pragma unroll
    for (int nb = 0; nb < 4; ++nb)
      __builtin_nontemporal_store(acc[nb][r] * rinv, orow + nb * 32);
  }
}

extern "C" void kernel_launch(void* const* d_in, const int* in_sizes, int n_in,
                              void* d_out, int out_size, void* d_ws, size_t ws_size,
                              hipStream_t stream) {
  const float* Q    = (const float*)d_in[0];
  const float* K    = (const float*)d_in[1];
  const float* V    = (const float*)d_in[2];
  const int*   Mask = (const int*)d_in[3];
  float*       Out  = (float*)d_out;
  (void)d_ws; (void)ws_size;
  attn_fwd<<<dim3(512), dim3(256), 0, stream>>>(Q, K, V, Mask, Out);
}